// Round 10
// baseline (371.093 us; speedup 1.0000x reference)
//
#include <hip/hip_runtime.h>
#include <stdint.h>

typedef unsigned short u16;
typedef __attribute__((ext_vector_type(8))) short short8;
typedef __attribute__((ext_vector_type(4))) float f32x4;
typedef __attribute__((ext_vector_type(4))) unsigned short u16x4;

#define DEV __device__ __forceinline__

DEV u16 f2bf(float f) {
  union { float f; unsigned u; } v; v.f = f;
  unsigned r = v.u + 0x7fffu + ((v.u >> 16) & 1u);
  return (u16)(r >> 16);
}
DEV float bf2f(u16 b) {
  union { unsigned u; float f; } v; v.u = ((unsigned)b) << 16;
  return v.f;
}
DEV void gload_lds16(const void* g, void* l) {
  __builtin_amdgcn_global_load_lds((const __attribute__((address_space(1))) void*)g,
                                   (__attribute__((address_space(3))) void*)l,
                                   16, 0, 0);
}
// raw barrier: no compiler-inserted vmcnt(0) drain (unlike __syncthreads)
DEV void block_barrier() {
  asm volatile("" ::: "memory");
  __builtin_amdgcn_s_barrier();
  asm volatile("" ::: "memory");
}

// ---------------- elementwise f32 -> bf16 (vectorized) ----------------
__global__ void k_conv(const float* __restrict__ in, u16* __restrict__ out, int n4) {
  int i = blockIdx.x * blockDim.x + threadIdx.x;
  if (i >= n4) return;
  const f32x4 v = *(const f32x4*)(in + (size_t)i * 4);
  u16x4 o;
  o[0] = f2bf(v[0]); o[1] = f2bf(v[1]); o[2] = f2bf(v[2]); o[3] = f2bf(v[3]);
  *(u16x4*)(out + (size_t)i * 4) = o;
}

// ---------------- transpose + convert: in f32 [R][C] -> out bf16 [C][R] ----------------
__global__ void k_tconv(const float* __restrict__ in, u16* __restrict__ out, int R, int C) {
  __shared__ float tile[32][33];
  int c0 = blockIdx.x * 32, r0 = blockIdx.y * 32;
  int tx = threadIdx.x, ty = threadIdx.y;
#pragma unroll
  for (int j = 0; j < 32; j += 8)
    tile[ty + j][tx] = in[(size_t)(r0 + ty + j) * C + (c0 + tx)];
  __syncthreads();
#pragma unroll
  for (int j = 0; j < 32; j += 8)
    out[(size_t)(c0 + ty + j) * R + (r0 + tx)] = f2bf(tile[tx][ty + j]);
}

// ======== QKV GEMM with fused RoPE/head-split/V-transpose epilogue v2 ========
// Main loop: 256x256, even 4-phase, counted vmcnt, T2 swizzle (= k_gemm3).
// Epilogue: stage 256x256 bf16 tile in the GEMM's 128 KB LDS (dead after final
// barrier), bank-swizzled; q/k rows get RoPE (q additionally PRE-SCALED by
// 1/sqrt(128)*log2e so attn's exp2 needs no multiply); v columns -> vt.
__global__ __launch_bounds__(512, 2) void k_gemmqkv(const u16* __restrict__ A,
                                                    const u16* __restrict__ Bt,
                                                    const float* __restrict__ bias,
                                                    u16* __restrict__ qh,
                                                    u16* __restrict__ kh,
                                                    u16* __restrict__ vt) {
  const int Kld = 2048, nt = 32;
  __shared__ __align__(16) short smem[4][256 * 64];  // [0..1]=lA dbuf, [2..3]=lB dbuf
  const int tid = threadIdx.x;
  const int wid = tid >> 6, lane = tid & 63;
  const int gx = gridDim.x;
  const int nwg = gx * gridDim.y;
  const int orig = blockIdx.y * gx + blockIdx.x;
  const int lg = (orig & 7) * (nwg >> 3) + (orig >> 3);
  const int bm = (lg % gx) * 256, bn = (lg / gx) * 256;
  const int wr = wid >> 2, wc = wid & 3;            // 2M x 4N wave grid
  const int r = lane & 15, kq = lane >> 4, r7 = lane & 7;

  int aoff[4], boff[4], lbase[4];
#pragma unroll
  for (int j = 0; j < 4; ++j) {
    int c = j * 512 + wid * 64 + lane;
    int row = c >> 3, ch = c & 7;
    aoff[j] = (bm + row) * Kld + (ch ^ (row & 7)) * 8;
    boff[j] = (bn + row) * Kld + (ch ^ (row & 7)) * 8;
    lbase[j] = (j * 512 + wid * 64) * 16;           // wave-uniform LDS byte base
  }

#define STG_A(k0, buf, j) gload_lds16(A + aoff[j] + (k0), (char*)&smem[(buf)][0] + lbase[j])
#define STG_B(k0, buf, j) gload_lds16(Bt + boff[j] + (k0), (char*)&smem[2 + (buf)][0] + lbase[j])
#define RD_A(AF, MH, KK)                                                        \
  _Pragma("unroll")                                                             \
  for (int m2 = 0; m2 < 4; ++m2)                                                \
    AF[m2] = *(const short8*)&As[(wr * 128 + (MH) * 64 + m2 * 16 + r) * 64      \
                                 + (((KK) * 4 + kq) ^ r7) * 8];
#define RD_B(KK)                                                                \
  _Pragma("unroll")                                                             \
  for (int nf = 0; nf < 4; ++nf)                                                \
    bfr[KK][nf] = *(const short8*)&Bs[(wc * 64 + nf * 16 + r) * 64              \
                                      + (((KK) * 4 + kq) ^ r7) * 8];
#define PH_MFMA(AF, MH, KK)                                                     \
  __builtin_amdgcn_s_setprio(1);                                                \
  _Pragma("unroll")                                                             \
  for (int m2 = 0; m2 < 4; ++m2)                                                \
    _Pragma("unroll")                                                           \
    for (int nf = 0; nf < 4; ++nf)                                              \
      acc[(MH) * 4 + m2][nf] = __builtin_amdgcn_mfma_f32_16x16x32_bf16(         \
          AF[m2], bfr[KK][nf], acc[(MH) * 4 + m2][nf], 0, 0, 0);                \
  __builtin_amdgcn_s_setprio(0);

  f32x4 acc[8][4];
  const f32x4 zero = {0.f, 0.f, 0.f, 0.f};
#pragma unroll
  for (int i = 0; i < 8; ++i)
#pragma unroll
    for (int j = 0; j < 4; ++j) acc[i][j] = zero;

#pragma unroll
  for (int j = 0; j < 4; ++j) STG_A(0, 0, j);
#pragma unroll
  for (int j = 0; j < 4; ++j) STG_B(0, 0, j);
#pragma unroll
  for (int j = 0; j < 4; ++j) STG_B(64, 1, j);
  asm volatile("s_waitcnt vmcnt(4)" ::: "memory");
  block_barrier();

#pragma unroll 1
  for (int t = 0; t < nt; ++t) {
    const int cur = t & 1, nxt = cur ^ 1;
    const short* As = &smem[cur][0];
    const short* Bs = &smem[2 + cur][0];
    const int kA = (t + 1) * 64, kB = (t + 2) * 64;
    const bool sA = (t + 1 < nt), sB = (t + 2 < nt);
    short8 bfr[2][4];
    short8 af[4];

    RD_B(0)
    RD_A(af, 0, 0)
    if (sA) { STG_A(kA, nxt, 0); STG_A(kA, nxt, 1); }
    block_barrier();
    PH_MFMA(af, 0, 0)
    block_barrier();

    RD_B(1)
    RD_A(af, 0, 1)
    if (sA) { STG_A(kA, nxt, 2); STG_A(kA, nxt, 3); }
    block_barrier();
    PH_MFMA(af, 0, 1)
    block_barrier();

    RD_A(af, 1, 0)
    if (sB) { STG_B(kB, cur, 0); STG_B(kB, cur, 1); }
    block_barrier();
    PH_MFMA(af, 1, 0)
    block_barrier();

    RD_A(af, 1, 1)
    if (sB) { STG_B(kB, cur, 2); STG_B(kB, cur, 3); }
    block_barrier();
    PH_MFMA(af, 1, 1)
    if (t + 1 < nt) {
      if (sB) asm volatile("s_waitcnt vmcnt(4)" ::: "memory");
      else    asm volatile("s_waitcnt vmcnt(0)" ::: "memory");
    }
    block_barrier();
  }
#undef STG_A
#undef STG_B
#undef RD_A
#undef RD_B
#undef PH_MFMA

  // -------- fused epilogue (LDS-staged, coalesced writes) --------
  const int by = lg / gx;            // 0..23
  const int part = by >> 3;          // 0=q, 1=k, 2=v
  const int b_ = bm >> 11;           // batch
  const int tb = bm & 2047;          // t base (block never crosses batch)
  const int hbase = (bn & 2047) >> 7;
  u16* ob = (u16*)&smem[0][0];       // 128 KB staging [256 ml][256 cl]

  // write phase: biased values -> ob (swizzled)
#pragma unroll
  for (int nf = 0; nf < 4; ++nf) {
    int nl = wc * 64 + nf * 16 + r;
    float bv = bias[bn + nl];
#pragma unroll
    for (int mf = 0; mf < 8; ++mf) {
      int mlb = wr * 128 + mf * 16 + kq * 4;
#pragma unroll
      for (int i = 0; i < 4; ++i) {
        int ml = mlb + i;
        int cl = (part == 2)
          ? (nl ^ (((ml >> 2) & 3) << 4) ^ (((ml >> 4) & 7) << 1))
          : (nl ^ (((ml >> 2) & 3) << 4));
        ob[ml * 256 + cl] = f2bf(acc[mf][nf][i] + bv);
      }
    }
  }
  block_barrier();

  if (part == 2) {
    // V: wave reads column dl = iter*8+wid; stores 512 B t-runs into vt
#pragma unroll 1
    for (int iter = 0; iter < 32; ++iter) {
      int dl = iter * 8 + wid;
      int hh = hbase + (dl >> 7), d = dl & 127;
      int tl4 = lane * 4;
      int cl = dl ^ ((lane & 3) << 4) ^ (((lane >> 2) & 7) << 1);
      u16x4 o;
#pragma unroll
      for (int j = 0; j < 4; ++j) o[j] = ob[(tl4 + j) * 256 + cl];
      *(u16x4*)(vt + ((size_t)(b_ * 16 + hh) * 128 + d) * 2048 + tb + tl4) = o;
    }
  } else {
    // q/k: wave reads row tl = iter*8+wid; RoPE pair (d, d^64) same row.
    // q additionally pre-scaled by 1/sqrt(128)*log2(e) for attn's exp2.
    u16* dst = part ? kh : qh;
    const float qscale = part ? 1.0f : 0.12751744766834352f;
    const int nl2 = lane * 4;
    const int hh = hbase + (nl2 >> 7);
    const int d0 = nl2 & 127;
    const int hi = (nl2 >> 6) & 1;
    float inv0 = exp2f((float)(nl2 & 63) * -0.20762050593045077f);  // 10000^(-dd/64)
    const float k1 = 0.8659643233600653f;                           // 10000^(-1/64)
    float invj[4];
    invj[0] = inv0; invj[1] = inv0 * k1; invj[2] = invj[1] * k1; invj[3] = invj[2] * k1;
#pragma unroll 1
    for (int iter = 0; iter < 32; ++iter) {
      int tl = iter * 8 + wid;
      float tg = (float)(tb + tl);
      int xr = ((tl >> 2) & 3) << 4;
      int base = tl * 256 + (nl2 ^ xr);
      int pbase = tl * 256 + ((nl2 ^ 64) ^ xr);
      u16x4 o;
#pragma unroll
      for (int j = 0; j < 4; ++j) {
        float vo = bf2f(ob[base + j]);
        float vp = bf2f(ob[pbase + j]);
        float sn, cs;
        sincosf(tg * invj[j], &sn, &cs);
        float vr = hi ? (vo * cs + vp * sn) : (vo * cs - vp * sn);
        o[j] = f2bf(vr * qscale);
      }
      *(u16x4*)(dst + ((size_t)(b_ * 16 + hh) * 2048 + (tb + tl)) * 128 + d0) = o;
    }
  }
}

// ---------------- GEMM TN v4 (proj split-K): 256x256, even 4-phase ----------
template <bool OUT_BF16, bool SPLITK>
__global__ __launch_bounds__(512, 2) void k_gemm3(const u16* __restrict__ A,
                                                  const u16* __restrict__ Bt,
                                                  const float* __restrict__ bias,
                                                  void* __restrict__ Cv,
                                                  int M, int N, int Kld, int nkt) {
  __shared__ __align__(16) short lA[2][256 * 64];   // 2 x 32 KB
  __shared__ __align__(16) short lB[2][256 * 64];   // 2 x 32 KB
  const int tid = threadIdx.x;
  const int wid = tid >> 6, lane = tid & 63;
  const int gx = gridDim.x;
  const int nwg = gx * gridDim.y;
  const int orig = blockIdx.y * gx + blockIdx.x;
  const int lg = (orig & 7) * (nwg >> 3) + (orig >> 3);
  const int bm = (lg % gx) * 256, bn = (lg / gx) * 256;
  const int wr = wid >> 2, wc = wid & 3;            // 2M x 4N wave grid
  const int r = lane & 15, kq = lane >> 4, r7 = lane & 7;
  const int kz = SPLITK ? blockIdx.z * (nkt << 6) : 0;

  int aoff[4], boff[4], lbase[4];
#pragma unroll
  for (int j = 0; j < 4; ++j) {
    int c = j * 512 + wid * 64 + lane;
    int row = c >> 3, ch = c & 7;
    aoff[j] = (bm + row) * Kld + kz + (ch ^ (row & 7)) * 8;
    boff[j] = (bn + row) * Kld + kz + (ch ^ (row & 7)) * 8;
    lbase[j] = (j * 512 + wid * 64) * 16;           // wave-uniform LDS byte base
  }

#define STG_A(k0, buf, j) gload_lds16(A + aoff[j] + (k0), (char*)&lA[(buf)][0] + lbase[j])
#define STG_B(k0, buf, j) gload_lds16(Bt + boff[j] + (k0), (char*)&lB[(buf)][0] + lbase[j])
#define RD_A(AF, MH, KK)                                                        \
  _Pragma("unroll")                                                             \
  for (int m2 = 0; m2 < 4; ++m2)                                                \
    AF[m2] = *(const short8*)&As[(wr * 128 + (MH) * 64 + m2 * 16 + r) * 64      \
                                 + (((KK) * 4 + kq) ^ r7) * 8];
#define RD_B(KK)                                                                \
  _Pragma("unroll")                                                             \
  for (int nf = 0; nf < 4; ++nf)                                                \
    bfr[KK][nf] = *(const short8*)&Bs[(wc * 64 + nf * 16 + r) * 64              \
                                      + (((KK) * 4 + kq) ^ r7) * 8];
#define PH_MFMA(AF, MH, KK)                                                     \
  __builtin_amdgcn_s_setprio(1);                                                \
  _Pragma("unroll")                                                             \
  for (int m2 = 0; m2 < 4; ++m2)                                                \
    _Pragma("unroll")                                                           \
    for (int nf = 0; nf < 4; ++nf)                                              \
      acc[(MH) * 4 + m2][nf] = __builtin_amdgcn_mfma_f32_16x16x32_bf16(         \
          AF[m2], bfr[KK][nf], acc[(MH) * 4 + m2][nf], 0, 0, 0);                \
  __builtin_amdgcn_s_setprio(0);

  f32x4 acc[8][4];
  const f32x4 zero = {0.f, 0.f, 0.f, 0.f};
#pragma unroll
  for (int i = 0; i < 8; ++i)
#pragma unroll
    for (int j = 0; j < 4; ++j) acc[i][j] = zero;

  const int nt = nkt;

#pragma unroll
  for (int j = 0; j < 4; ++j) STG_A(0, 0, j);
#pragma unroll
  for (int j = 0; j < 4; ++j) STG_B(0, 0, j);
  if (nt > 1) {
#pragma unroll
    for (int j = 0; j < 4; ++j) STG_B(64, 1, j);
    asm volatile("s_waitcnt vmcnt(4)" ::: "memory");
  } else {
    asm volatile("s_waitcnt vmcnt(0)" ::: "memory");
  }
  block_barrier();

#pragma unroll 1
  for (int t = 0; t < nt; ++t) {
    const int cur = t & 1, nxt = cur ^ 1;
    const short* As = &lA[cur][0];
    const short* Bs = &lB[cur][0];
    const int kA = (t + 1) * 64, kB = (t + 2) * 64;
    const bool sA = (t + 1 < nt), sB = (t + 2 < nt);
    short8 bfr[2][4];
    short8 af[4];

    RD_B(0)
    RD_A(af, 0, 0)
    if (sA) { STG_A(kA, nxt, 0); STG_A(kA, nxt, 1); }
    block_barrier();
    PH_MFMA(af, 0, 0)
    block_barrier();

    RD_B(1)
    RD_A(af, 0, 1)
    if (sA) { STG_A(kA, nxt, 2); STG_A(kA, nxt, 3); }
    block_barrier();
    PH_MFMA(af, 0, 1)
    block_barrier();

    RD_A(af, 1, 0)
    if (sB) { STG_B(kB, cur, 0); STG_B(kB, cur, 1); }
    block_barrier();
    PH_MFMA(af, 1, 0)
    block_barrier();

    RD_A(af, 1, 1)
    if (sB) { STG_B(kB, cur, 2); STG_B(kB, cur, 3); }
    block_barrier();
    PH_MFMA(af, 1, 1)
    if (t + 1 < nt) {
      if (sB) asm volatile("s_waitcnt vmcnt(4)" ::: "memory");
      else    asm volatile("s_waitcnt vmcnt(0)" ::: "memory");
    }
    block_barrier();
  }
#undef STG_A
#undef STG_B
#undef RD_A
#undef RD_B
#undef PH_MFMA

#pragma unroll
  for (int mf = 0; mf < 8; ++mf)
#pragma unroll
    for (int nf = 0; nf < 4; ++nf) {
      int n = bn + wc * 64 + nf * 16 + r;
      float bv = SPLITK ? 0.f : bias[n];
#pragma unroll
      for (int i = 0; i < 4; ++i) {
        int m = bm + wr * 128 + mf * 16 + kq * 4 + i;
        float val = acc[mf][nf][i] + bv;
        if (SPLITK)
          ((float*)Cv)[(size_t)blockIdx.z * M * N + (size_t)m * N + n] = val;
        else if (OUT_BF16)
          ((u16*)Cv)[(size_t)m * N + n] = f2bf(val);
        else
          ((float*)Cv)[(size_t)m * N + n] = val;
      }
    }
}

// ---------------- split-K reduce: y = p0 + p1 + bias (fp32, N=2048) ----------
__global__ void k_fadd(const float* __restrict__ p, const float* __restrict__ bias,
                       float* __restrict__ y, int n4) {
  const int half4 = 2097152;  // 4096*2048/4
  for (int i = blockIdx.x * blockDim.x + threadIdx.x; i < n4; i += gridDim.x * blockDim.x) {
    f32x4 a = *(const f32x4*)(p + (size_t)i * 4);
    f32x4 b = *(const f32x4*)(p + (size_t)(i + half4) * 4);
    f32x4 bv = *(const f32x4*)(bias + ((i & 511) << 2));
    f32x4 o = a + b + bv;
    *(f32x4*)(y + (size_t)i * 4) = o;
  }
}

// ---------------- causal flash attention v4: V from L2, K-only staging -------
// Balanced pairing (block p: q-tiles p and 31-p, QBLK=64, KBLK=64; 33 tiles).
// Max-free softmax (q pre-scaled; exp2 direct). NEW (Common-mistake #7):
// V is NOT LDS-staged -- per bh K+V = 1 MB, L2-resident (16 blocks share bh);
// PV's 16 B-fragments load directly from global right after the barrier, so
// their L2 latency hides under QK+exp2. K staging halves: 4 gload_lds/tile,
// vmcnt(4). LDS 72->40 KB.
__global__ __launch_bounds__(256, 2) void k_attn(const u16* __restrict__ qh,
                                                 const u16* __restrict__ kh,
                                                 const u16* __restrict__ vt,
                                                 u16* __restrict__ out) {
  __shared__ __align__(16) short lK[2][64 * 128];   // 32 KB (swizzled rows of 256 B)
  __shared__ __align__(16) short lP[64 * 64];       // 8 KB  (wave-private rows, swizzled)
  const int tid = threadIdx.x, wid = tid >> 6, lane = tid & 63;
  const int p = blockIdx.x, h = blockIdx.y, b = blockIdx.z;
  const size_t bh = (size_t)b * 16 + h;
  const u16* qb = qh + bh * 2048 * 128;
  const u16* kb = kh + bh * 2048 * 128;
  const u16* vb = vt + bh * 128 * 2048;
  const int r = lane & 15, kq = lane >> 4;
  const int r7 = r & 7;
  const int wrow = wid * 16;

  // K staging source offsets (tile-invariant part); source chunk pre-swizzled
  int koff[4];
#pragma unroll
  for (int i = 0; i < 4; ++i) {
    int ci = (wid * 4 + i) * 64 + lane;
    int krow = ci >> 4, kch = ci & 15;          // K tile: 64 rows x 16 chunks(16B)
    koff[i] = krow * 128 + ((kch ^ (krow & 7)) * 8);
  }

#pragma unroll 1
  for (int seg = 0; seg < 2; ++seg) {
    const int j = seg ? 31 - p : p;
    const int q0 = j * 64;
    const int nkt = j + 1;

    short8 qa[4];
#pragma unroll
    for (int kk = 0; kk < 4; ++kk)
      qa[kk] = *(const short8*)(qb + (size_t)(q0 + wrow + r) * 128 + kk * 32 + kq * 8);

    f32x4 O[8];
    const f32x4 zero = {0.f, 0.f, 0.f, 0.f};
#pragma unroll
    for (int nf = 0; nf < 8; ++nf) O[nf] = zero;
    float lp[4] = {0.f, 0.f, 0.f, 0.f};   // per-lane row-sum partials

    // prologue: stage K tile 0 -> buf 0
#pragma unroll
    for (int i = 0; i < 4; ++i)
      gload_lds16(kb + koff[i], (char*)&lK[0][0] + (wid * 4 + i) * 1024);

#pragma unroll 1
    for (int kt = 0; kt < nkt; ++kt) {
      const int cur = kt & 1;
      const int kt0 = kt * 64;
      if (kt + 1 < nkt) {
        const size_t kbase = (size_t)(kt + 1) * 8192;
#pragma unroll
        for (int i = 0; i < 4; ++i)
          gload_lds16(kb + kbase + koff[i], (char*)&lK[cur ^ 1][0] + (wid * 4 + i) * 1024);
        asm volatile("s_waitcnt vmcnt(4)" ::: "memory");  // K(t) landed; K(t+1) in flight
      } else {
        asm volatile("s_waitcnt vmcnt(0)" ::: "memory");
      }
      block_barrier();

      // V fragments direct from global (L2-resident); issued before QK so the
      // latency hides under QK+exp2. 16 x 16B per lane.
      short8 vf[8][2];
#pragma unroll
      for (int nf = 0; nf < 8; ++nf)
#pragma unroll
        for (int kk = 0; kk < 2; ++kk)
          vf[nf][kk] = *(const short8*)(vb + (size_t)(nf * 16 + r) * 2048 + kt0 + kk * 32 + kq * 8);

      // S = Q @ K^T (q pre-scaled by 1/sqrt(128)*log2e)
      f32x4 S[4];
#pragma unroll
      for (int nf = 0; nf < 4; ++nf) S[nf] = zero;
#pragma unroll
      for (int kk = 0; kk < 4; ++kk) {
        short8 kf[4];
#pragma unroll
        for (int nf = 0; nf < 4; ++nf)
          kf[nf] = *(const short8*)&lK[cur][(nf * 16 + r) * 128 + ((kk * 4 + kq) ^ r7) * 8];
#pragma unroll
        for (int nf = 0; nf < 4; ++nf)
          S[nf] = __builtin_amdgcn_mfma_f32_16x16x32_bf16(qa[kk], kf[nf], S[nf], 0, 0, 0);
      }

      // P = exp2(S) un-normalized (0 where masked)
      const bool diag = (kt == nkt - 1);
#pragma unroll
      for (int nf = 0; nf < 4; ++nf)
#pragma unroll
        for (int i = 0; i < 4; ++i) {
          float pv = exp2f(S[nf][i]);
          if (diag) {
            int kg = kt0 + nf * 16 + r;
            int qg = q0 + wrow + kq * 4 + i;
            pv = (kg > qg) ? 0.f : pv;
          }
          lp[i] += pv;
          int row = wrow + kq * 4 + i;
          int cl = (nf * 2 + (r >> 3)) ^ ((kq * 4 + i) & 7);
          lP[row * 64 + cl * 8 + r7] = (short)f2bf(pv);
        }

      // O += P @ V^T (P rows wave-private; V in registers)
#pragma unroll
      for (int kk = 0; kk < 2; ++kk) {
        short8 pa = *(const short8*)&lP[(wrow + r) * 64 + ((kk * 4 + kq) ^ r7) * 8];
#pragma unroll
        for (int nf = 0; nf < 8; ++nf)
          O[nf] = __builtin_amdgcn_mfma_f32_16x16x32_bf16(pa, vf[nf][kk], O[nf], 0, 0, 0);
      }
      asm volatile("s_waitcnt lgkmcnt(0)" ::: "memory");
      block_barrier();  // all K reads done before next stage overwrites
    }

    // finalize: one deferred row-sum reduce, then O/l
    float inv[4];
#pragma unroll
    for (int i = 0; i < 4; ++i) {
      float v = lp[i];
      v += __shfl_xor(v, 1);
      v += __shfl_xor(v, 2);
      v += __shfl_xor(v, 4);
      v += __shfl_xor(v, 8);
      inv[i] = 1.f / v;
    }
#pragma unroll
    for (int nf = 0; nf < 8; ++nf)
#pragma unroll
      for (int i = 0; i < 4; ++i) {
        int qg = q0 + wrow + kq * 4 + i;
        out[(size_t)(b * 2048 + qg) * 2048 + h * 128 + nf * 16 + r] = f2bf(O[nf][i] * inv[i]);
      }
  }
}

extern "C" void kernel_launch(void* const* d_in, const int* in_sizes, int n_in,
                              void* d_out, int out_size, void* d_ws, size_t ws_size,
                              hipStream_t stream) {
  const float* x      = (const float*)d_in[0];
  const float* W_attn = (const float*)d_in[1];
  const float* b_attn = (const float*)d_in[2];
  const float* W_proj = (const float*)d_in[3];
  const float* b_proj = (const float*)d_in[4];
  float* y = (float*)d_out;

  // workspace carve-up (bf16 buffers), total 160 MB
  u16* xb     = (u16*)d_ws;                      // [4096][2048]   MB  0-16
  u16* wqkvT  = xb     + (size_t)4096 * 2048;    // [6144][2048]   MB 16-40
  u16* wprojT = wqkvT  + (size_t)6144 * 2048;    // [2048][2048]   MB 40-48
  u16* qkv    = wprojT + (size_t)2048 * 2048;    // (free region)  MB 48-96
  u16* qh     = qkv    + (size_t)4096 * 6144;    // [32][2048][128] 96-112
  u16* kh     = qh     + (size_t)4096 * 2048;    //               112-128
  u16* vt     = kh     + (size_t)4096 * 2048;    // [32][128][2048] 128-144
  u16* attout = vt     + (size_t)4096 * 2048;    // [4096][2048]  144-160
  if (ws_size < (size_t)83886080 * 2) return;    // need 160 MB

  // proj split-K fp32 partials (64 MB) alias the free region
  float* pproj = (float*)qkv;

  k_conv<<<8192, 256, 0, stream>>>(x, xb, 2097152);
  k_tconv<<<dim3(192, 64), dim3(32, 8), 0, stream>>>(W_attn, wqkvT, 2048, 6144);
  k_tconv<<<dim3(64, 64), dim3(32, 8), 0, stream>>>(W_proj, wprojT, 2048, 2048);
  k_gemmqkv<<<dim3(16, 24), 512, 0, stream>>>(xb, wqkvT, b_attn, qh, kh, vt);
  k_attn<<<dim3(16, 16, 2), 256, 0, stream>>>(qh, kh, vt, attout);
  k_gemm3<false, true><<<dim3(16, 8, 2), 512, 0, stream>>>(attout, wprojT, b_proj, pproj, 4096, 2048, 2048, 16);
  k_fadd<<<2048, 256, 0, stream>>>(pproj, b_proj, y, 2097152);
}

// Round 11
// 319.807 us; speedup vs baseline: 1.1604x; 1.1604x over previous
//
#include <hip/hip_runtime.h>
#include <stdint.h>

typedef unsigned short u16;
typedef __attribute__((ext_vector_type(8))) short short8;
typedef __attribute__((ext_vector_type(4))) float f32x4;
typedef __attribute__((ext_vector_type(4))) unsigned short u16x4;

#define DEV __device__ __forceinline__

DEV u16 f2bf(float f) {
  union { float f; unsigned u; } v; v.f = f;
  unsigned r = v.u + 0x7fffu + ((v.u >> 16) & 1u);
  return (u16)(r >> 16);
}
DEV float bf2f(u16 b) {
  union { unsigned u; float f; } v; v.u = ((unsigned)b) << 16;
  return v.f;
}
DEV void gload_lds16(const void* g, void* l) {
  __builtin_amdgcn_global_load_lds((const __attribute__((address_space(1))) void*)g,
                                   (__attribute__((address_space(3))) void*)l,
                                   16, 0, 0);
}
// raw barrier: no compiler-inserted vmcnt(0) drain (unlike __syncthreads)
DEV void block_barrier() {
  asm volatile("" ::: "memory");
  __builtin_amdgcn_s_barrier();
  asm volatile("" ::: "memory");
}

// ---------------- elementwise f32 -> bf16 (vectorized) ----------------
__global__ void k_conv(const float* __restrict__ in, u16* __restrict__ out, int n4) {
  int i = blockIdx.x * blockDim.x + threadIdx.x;
  if (i >= n4) return;
  const f32x4 v = *(const f32x4*)(in + (size_t)i * 4);
  u16x4 o;
  o[0] = f2bf(v[0]); o[1] = f2bf(v[1]); o[2] = f2bf(v[2]); o[3] = f2bf(v[3]);
  *(u16x4*)(out + (size_t)i * 4) = o;
}

// ---------------- transpose + convert: in f32 [R][C] -> out bf16 [C][R] ----------------
__global__ void k_tconv(const float* __restrict__ in, u16* __restrict__ out, int R, int C) {
  __shared__ float tile[32][33];
  int c0 = blockIdx.x * 32, r0 = blockIdx.y * 32;
  int tx = threadIdx.x, ty = threadIdx.y;
#pragma unroll
  for (int j = 0; j < 32; j += 8)
    tile[ty + j][tx] = in[(size_t)(r0 + ty + j) * C + (c0 + tx)];
  __syncthreads();
#pragma unroll
  for (int j = 0; j < 32; j += 8)
    out[(size_t)(c0 + ty + j) * R + (r0 + tx)] = f2bf(tile[tx][ty + j]);
}

// ======== QKV GEMM with fused RoPE/head-split/V-transpose epilogue v2 ========
// Main loop: 256x256, even 4-phase, counted vmcnt, T2 swizzle (= k_gemm3).
// Epilogue: stage 256x256 bf16 tile in the GEMM's 128 KB LDS (dead after final
// barrier), bank-swizzled; q/k rows get RoPE (q additionally PRE-SCALED by
// 1/sqrt(128)*log2e so attn's exp2 needs no multiply); v columns -> vt.
__global__ __launch_bounds__(512, 2) void k_gemmqkv(const u16* __restrict__ A,
                                                    const u16* __restrict__ Bt,
                                                    const float* __restrict__ bias,
                                                    u16* __restrict__ qh,
                                                    u16* __restrict__ kh,
                                                    u16* __restrict__ vt) {
  const int Kld = 2048, nt = 32;
  __shared__ __align__(16) short smem[4][256 * 64];  // [0..1]=lA dbuf, [2..3]=lB dbuf
  const int tid = threadIdx.x;
  const int wid = tid >> 6, lane = tid & 63;
  const int gx = gridDim.x;
  const int nwg = gx * gridDim.y;
  const int orig = blockIdx.y * gx + blockIdx.x;
  const int lg = (orig & 7) * (nwg >> 3) + (orig >> 3);
  const int bm = (lg % gx) * 256, bn = (lg / gx) * 256;
  const int wr = wid >> 2, wc = wid & 3;            // 2M x 4N wave grid
  const int r = lane & 15, kq = lane >> 4, r7 = lane & 7;

  int aoff[4], boff[4], lbase[4];
#pragma unroll
  for (int j = 0; j < 4; ++j) {
    int c = j * 512 + wid * 64 + lane;
    int row = c >> 3, ch = c & 7;
    aoff[j] = (bm + row) * Kld + (ch ^ (row & 7)) * 8;
    boff[j] = (bn + row) * Kld + (ch ^ (row & 7)) * 8;
    lbase[j] = (j * 512 + wid * 64) * 16;           // wave-uniform LDS byte base
  }

#define STG_A(k0, buf, j) gload_lds16(A + aoff[j] + (k0), (char*)&smem[(buf)][0] + lbase[j])
#define STG_B(k0, buf, j) gload_lds16(Bt + boff[j] + (k0), (char*)&smem[2 + (buf)][0] + lbase[j])
#define RD_A(AF, MH, KK)                                                        \
  _Pragma("unroll")                                                             \
  for (int m2 = 0; m2 < 4; ++m2)                                                \
    AF[m2] = *(const short8*)&As[(wr * 128 + (MH) * 64 + m2 * 16 + r) * 64      \
                                 + (((KK) * 4 + kq) ^ r7) * 8];
#define RD_B(KK)                                                                \
  _Pragma("unroll")                                                             \
  for (int nf = 0; nf < 4; ++nf)                                                \
    bfr[KK][nf] = *(const short8*)&Bs[(wc * 64 + nf * 16 + r) * 64              \
                                      + (((KK) * 4 + kq) ^ r7) * 8];
#define PH_MFMA(AF, MH, KK)                                                     \
  __builtin_amdgcn_s_setprio(1);                                                \
  _Pragma("unroll")                                                             \
  for (int m2 = 0; m2 < 4; ++m2)                                                \
    _Pragma("unroll")                                                           \
    for (int nf = 0; nf < 4; ++nf)                                              \
      acc[(MH) * 4 + m2][nf] = __builtin_amdgcn_mfma_f32_16x16x32_bf16(         \
          AF[m2], bfr[KK][nf], acc[(MH) * 4 + m2][nf], 0, 0, 0);                \
  __builtin_amdgcn_s_setprio(0);

  f32x4 acc[8][4];
  const f32x4 zero = {0.f, 0.f, 0.f, 0.f};
#pragma unroll
  for (int i = 0; i < 8; ++i)
#pragma unroll
    for (int j = 0; j < 4; ++j) acc[i][j] = zero;

#pragma unroll
  for (int j = 0; j < 4; ++j) STG_A(0, 0, j);
#pragma unroll
  for (int j = 0; j < 4; ++j) STG_B(0, 0, j);
#pragma unroll
  for (int j = 0; j < 4; ++j) STG_B(64, 1, j);
  asm volatile("s_waitcnt vmcnt(4)" ::: "memory");
  block_barrier();

#pragma unroll 1
  for (int t = 0; t < nt; ++t) {
    const int cur = t & 1, nxt = cur ^ 1;
    const short* As = &smem[cur][0];
    const short* Bs = &smem[2 + cur][0];
    const int kA = (t + 1) * 64, kB = (t + 2) * 64;
    const bool sA = (t + 1 < nt), sB = (t + 2 < nt);
    short8 bfr[2][4];
    short8 af[4];

    RD_B(0)
    RD_A(af, 0, 0)
    if (sA) { STG_A(kA, nxt, 0); STG_A(kA, nxt, 1); }
    block_barrier();
    PH_MFMA(af, 0, 0)
    block_barrier();

    RD_B(1)
    RD_A(af, 0, 1)
    if (sA) { STG_A(kA, nxt, 2); STG_A(kA, nxt, 3); }
    block_barrier();
    PH_MFMA(af, 0, 1)
    block_barrier();

    RD_A(af, 1, 0)
    if (sB) { STG_B(kB, cur, 0); STG_B(kB, cur, 1); }
    block_barrier();
    PH_MFMA(af, 1, 0)
    block_barrier();

    RD_A(af, 1, 1)
    if (sB) { STG_B(kB, cur, 2); STG_B(kB, cur, 3); }
    block_barrier();
    PH_MFMA(af, 1, 1)
    if (t + 1 < nt) {
      if (sB) asm volatile("s_waitcnt vmcnt(4)" ::: "memory");
      else    asm volatile("s_waitcnt vmcnt(0)" ::: "memory");
    }
    block_barrier();
  }
#undef STG_A
#undef STG_B
#undef RD_A
#undef RD_B
#undef PH_MFMA

  // -------- fused epilogue (LDS-staged, coalesced writes) --------
  const int by = lg / gx;            // 0..23
  const int part = by >> 3;          // 0=q, 1=k, 2=v
  const int b_ = bm >> 11;           // batch
  const int tb = bm & 2047;          // t base (block never crosses batch)
  const int hbase = (bn & 2047) >> 7;
  u16* ob = (u16*)&smem[0][0];       // 128 KB staging [256 ml][256 cl]

  // write phase: biased values -> ob (swizzled)
#pragma unroll
  for (int nf = 0; nf < 4; ++nf) {
    int nl = wc * 64 + nf * 16 + r;
    float bv = bias[bn + nl];
#pragma unroll
    for (int mf = 0; mf < 8; ++mf) {
      int mlb = wr * 128 + mf * 16 + kq * 4;
#pragma unroll
      for (int i = 0; i < 4; ++i) {
        int ml = mlb + i;
        int cl = (part == 2)
          ? (nl ^ (((ml >> 2) & 3) << 4) ^ (((ml >> 4) & 7) << 1))
          : (nl ^ (((ml >> 2) & 3) << 4));
        ob[ml * 256 + cl] = f2bf(acc[mf][nf][i] + bv);
      }
    }
  }
  block_barrier();

  if (part == 2) {
    // V: wave reads column dl = iter*8+wid; stores 512 B t-runs into vt
#pragma unroll 1
    for (int iter = 0; iter < 32; ++iter) {
      int dl = iter * 8 + wid;
      int hh = hbase + (dl >> 7), d = dl & 127;
      int tl4 = lane * 4;
      int cl = dl ^ ((lane & 3) << 4) ^ (((lane >> 2) & 7) << 1);
      u16x4 o;
#pragma unroll
      for (int j = 0; j < 4; ++j) o[j] = ob[(tl4 + j) * 256 + cl];
      *(u16x4*)(vt + ((size_t)(b_ * 16 + hh) * 128 + d) * 2048 + tb + tl4) = o;
    }
  } else {
    // q/k: wave reads row tl = iter*8+wid; RoPE pair (d, d^64) same row.
    // q additionally pre-scaled by 1/sqrt(128)*log2(e) for attn's exp2.
    u16* dst = part ? kh : qh;
    const float qscale = part ? 1.0f : 0.12751744766834352f;
    const int nl2 = lane * 4;
    const int hh = hbase + (nl2 >> 7);
    const int d0 = nl2 & 127;
    const int hi = (nl2 >> 6) & 1;
    float inv0 = exp2f((float)(nl2 & 63) * -0.20762050593045077f);  // 10000^(-dd/64)
    const float k1 = 0.8659643233600653f;                           // 10000^(-1/64)
    float invj[4];
    invj[0] = inv0; invj[1] = inv0 * k1; invj[2] = invj[1] * k1; invj[3] = invj[2] * k1;
#pragma unroll 1
    for (int iter = 0; iter < 32; ++iter) {
      int tl = iter * 8 + wid;
      float tg = (float)(tb + tl);
      int xr = ((tl >> 2) & 3) << 4;
      int base = tl * 256 + (nl2 ^ xr);
      int pbase = tl * 256 + ((nl2 ^ 64) ^ xr);
      u16x4 o;
#pragma unroll
      for (int j = 0; j < 4; ++j) {
        float vo = bf2f(ob[base + j]);
        float vp = bf2f(ob[pbase + j]);
        float sn, cs;
        sincosf(tg * invj[j], &sn, &cs);
        float vr = hi ? (vo * cs + vp * sn) : (vo * cs - vp * sn);
        o[j] = f2bf(vr * qscale);
      }
      *(u16x4*)(dst + ((size_t)(b_ * 16 + hh) * 2048 + (tb + tl)) * 128 + d0) = o;
    }
  }
}

// ---------------- GEMM TN v4 (proj split-K): 256x256, even 4-phase ----------
template <bool OUT_BF16, bool SPLITK>
__global__ __launch_bounds__(512, 2) void k_gemm3(const u16* __restrict__ A,
                                                  const u16* __restrict__ Bt,
                                                  const float* __restrict__ bias,
                                                  void* __restrict__ Cv,
                                                  int M, int N, int Kld, int nkt) {
  __shared__ __align__(16) short lA[2][256 * 64];   // 2 x 32 KB
  __shared__ __align__(16) short lB[2][256 * 64];   // 2 x 32 KB
  const int tid = threadIdx.x;
  const int wid = tid >> 6, lane = tid & 63;
  const int gx = gridDim.x;
  const int nwg = gx * gridDim.y;
  const int orig = blockIdx.y * gx + blockIdx.x;
  const int lg = (orig & 7) * (nwg >> 3) + (orig >> 3);
  const int bm = (lg % gx) * 256, bn = (lg / gx) * 256;
  const int wr = wid >> 2, wc = wid & 3;            // 2M x 4N wave grid
  const int r = lane & 15, kq = lane >> 4, r7 = lane & 7;
  const int kz = SPLITK ? blockIdx.z * (nkt << 6) : 0;

  int aoff[4], boff[4], lbase[4];
#pragma unroll
  for (int j = 0; j < 4; ++j) {
    int c = j * 512 + wid * 64 + lane;
    int row = c >> 3, ch = c & 7;
    aoff[j] = (bm + row) * Kld + kz + (ch ^ (row & 7)) * 8;
    boff[j] = (bn + row) * Kld + kz + (ch ^ (row & 7)) * 8;
    lbase[j] = (j * 512 + wid * 64) * 16;           // wave-uniform LDS byte base
  }

#define STG_A(k0, buf, j) gload_lds16(A + aoff[j] + (k0), (char*)&lA[(buf)][0] + lbase[j])
#define STG_B(k0, buf, j) gload_lds16(Bt + boff[j] + (k0), (char*)&lB[(buf)][0] + lbase[j])
#define RD_A(AF, MH, KK)                                                        \
  _Pragma("unroll")                                                             \
  for (int m2 = 0; m2 < 4; ++m2)                                                \
    AF[m2] = *(const short8*)&As[(wr * 128 + (MH) * 64 + m2 * 16 + r) * 64      \
                                 + (((KK) * 4 + kq) ^ r7) * 8];
#define RD_B(KK)                                                                \
  _Pragma("unroll")                                                             \
  for (int nf = 0; nf < 4; ++nf)                                                \
    bfr[KK][nf] = *(const short8*)&Bs[(wc * 64 + nf * 16 + r) * 64              \
                                      + (((KK) * 4 + kq) ^ r7) * 8];
#define PH_MFMA(AF, MH, KK)                                                     \
  __builtin_amdgcn_s_setprio(1);                                                \
  _Pragma("unroll")                                                             \
  for (int m2 = 0; m2 < 4; ++m2)                                                \
    _Pragma("unroll")                                                           \
    for (int nf = 0; nf < 4; ++nf)                                              \
      acc[(MH) * 4 + m2][nf] = __builtin_amdgcn_mfma_f32_16x16x32_bf16(         \
          AF[m2], bfr[KK][nf], acc[(MH) * 4 + m2][nf], 0, 0, 0);                \
  __builtin_amdgcn_s_setprio(0);

  f32x4 acc[8][4];
  const f32x4 zero = {0.f, 0.f, 0.f, 0.f};
#pragma unroll
  for (int i = 0; i < 8; ++i)
#pragma unroll
    for (int j = 0; j < 4; ++j) acc[i][j] = zero;

  const int nt = nkt;

#pragma unroll
  for (int j = 0; j < 4; ++j) STG_A(0, 0, j);
#pragma unroll
  for (int j = 0; j < 4; ++j) STG_B(0, 0, j);
  if (nt > 1) {
#pragma unroll
    for (int j = 0; j < 4; ++j) STG_B(64, 1, j);
    asm volatile("s_waitcnt vmcnt(4)" ::: "memory");
  } else {
    asm volatile("s_waitcnt vmcnt(0)" ::: "memory");
  }
  block_barrier();

#pragma unroll 1
  for (int t = 0; t < nt; ++t) {
    const int cur = t & 1, nxt = cur ^ 1;
    const short* As = &lA[cur][0];
    const short* Bs = &lB[cur][0];
    const int kA = (t + 1) * 64, kB = (t + 2) * 64;
    const bool sA = (t + 1 < nt), sB = (t + 2 < nt);
    short8 bfr[2][4];
    short8 af[4];

    RD_B(0)
    RD_A(af, 0, 0)
    if (sA) { STG_A(kA, nxt, 0); STG_A(kA, nxt, 1); }
    block_barrier();
    PH_MFMA(af, 0, 0)
    block_barrier();

    RD_B(1)
    RD_A(af, 0, 1)
    if (sA) { STG_A(kA, nxt, 2); STG_A(kA, nxt, 3); }
    block_barrier();
    PH_MFMA(af, 0, 1)
    block_barrier();

    RD_A(af, 1, 0)
    if (sB) { STG_B(kB, cur, 0); STG_B(kB, cur, 1); }
    block_barrier();
    PH_MFMA(af, 1, 0)
    block_barrier();

    RD_A(af, 1, 1)
    if (sB) { STG_B(kB, cur, 2); STG_B(kB, cur, 3); }
    block_barrier();
    PH_MFMA(af, 1, 1)
    if (t + 1 < nt) {
      if (sB) asm volatile("s_waitcnt vmcnt(4)" ::: "memory");
      else    asm volatile("s_waitcnt vmcnt(0)" ::: "memory");
    }
    block_barrier();
  }
#undef STG_A
#undef STG_B
#undef RD_A
#undef RD_B
#undef PH_MFMA

#pragma unroll
  for (int mf = 0; mf < 8; ++mf)
#pragma unroll
    for (int nf = 0; nf < 4; ++nf) {
      int n = bn + wc * 64 + nf * 16 + r;
      float bv = SPLITK ? 0.f : bias[n];
#pragma unroll
      for (int i = 0; i < 4; ++i) {
        int m = bm + wr * 128 + mf * 16 + kq * 4 + i;
        float val = acc[mf][nf][i] + bv;
        if (SPLITK)
          ((float*)Cv)[(size_t)blockIdx.z * M * N + (size_t)m * N + n] = val;
        else if (OUT_BF16)
          ((u16*)Cv)[(size_t)m * N + n] = f2bf(val);
        else
          ((float*)Cv)[(size_t)m * N + n] = val;
      }
    }
}

// ---------------- split-K reduce: y = p0 + p1 + bias (fp32, N=2048) ----------
__global__ void k_fadd(const float* __restrict__ p, const float* __restrict__ bias,
                       float* __restrict__ y, int n4) {
  const int half4 = 2097152;  // 4096*2048/4
  for (int i = blockIdx.x * blockDim.x + threadIdx.x; i < n4; i += gridDim.x * blockDim.x) {
    f32x4 a = *(const f32x4*)(p + (size_t)i * 4);
    f32x4 b = *(const f32x4*)(p + (size_t)(i + half4) * 4);
    f32x4 bv = *(const f32x4*)(bias + ((i & 511) << 2));
    f32x4 o = a + b + bv;
    *(f32x4*)(y + (size_t)i * 4) = o;
  }
}

// ---------------- causal flash attention v5 = v3 (revert of v4) + exp2-direct
// Balanced pairing (block p: q-tiles p and 31-p, QBLK=64, KBLK=64; 33 tiles).
// K+V double-buffered LDS staging via gload_lds (coalesced), counted vmcnt(8),
// T2 swizzle. Max-free softmax; q arrives PRE-SCALED by 1/sqrt(128)*log2e so
// exp2 consumes S directly (no per-tile multiply). R10's V-from-L2 reverted:
// per-lane V fragment loads were uncoalesced (16 rows/instr) and unhidden at
// 2 waves/SIMD -- staging via global_load_lds is the cheap path.
__global__ __launch_bounds__(256) void k_attn(const u16* __restrict__ qh,
                                              const u16* __restrict__ kh,
                                              const u16* __restrict__ vt,
                                              u16* __restrict__ out) {
  __shared__ __align__(16) short lK[2][64 * 128];   // 32 KB (swizzled rows of 256 B)
  __shared__ __align__(16) short lV[2][128 * 64];   // 32 KB (swizzled rows of 128 B)
  __shared__ __align__(16) short lP[64 * 64];       // 8 KB  (wave-private rows, swizzled)
  const int tid = threadIdx.x, wid = tid >> 6, lane = tid & 63;
  const int p = blockIdx.x, h = blockIdx.y, b = blockIdx.z;
  const size_t bh = (size_t)b * 16 + h;
  const u16* qb = qh + bh * 2048 * 128;
  const u16* kb = kh + bh * 2048 * 128;
  const u16* vb = vt + bh * 128 * 2048;
  const int r = lane & 15, kq = lane >> 4;
  const int r7 = r & 7;
  const int wrow = wid * 16;

  int koff[4], voff[4];
#pragma unroll
  for (int i = 0; i < 4; ++i) {
    int ci = (wid * 4 + i) * 64 + lane;
    int krow = ci >> 4, kch = ci & 15;          // K tile: 64 rows x 16 chunks(16B)
    koff[i] = krow * 128 + ((kch ^ (krow & 7)) * 8);
    int vrow = ci >> 3, vch = ci & 7;           // V tile: 128 rows x 8 chunks(16B)
    voff[i] = vrow * 2048 + ((vch ^ (vrow & 7)) * 8);
  }

#pragma unroll 1
  for (int seg = 0; seg < 2; ++seg) {
    const int j = seg ? 31 - p : p;
    const int q0 = j * 64;
    const int nkt = j + 1;

    short8 qa[4];
#pragma unroll
    for (int kk = 0; kk < 4; ++kk)
      qa[kk] = *(const short8*)(qb + (size_t)(q0 + wrow + r) * 128 + kk * 32 + kq * 8);

    f32x4 O[8];
    const f32x4 zero = {0.f, 0.f, 0.f, 0.f};
#pragma unroll
    for (int nf = 0; nf < 8; ++nf) O[nf] = zero;
    float lp[4] = {0.f, 0.f, 0.f, 0.f};   // per-lane row-sum partials

    // prologue stage tile 0 -> buf 0
#pragma unroll
    for (int i = 0; i < 4; ++i) {
      gload_lds16(kb + koff[i], (char*)&lK[0][0] + (wid * 4 + i) * 1024);
      gload_lds16(vb + voff[i], (char*)&lV[0][0] + (wid * 4 + i) * 1024);
    }

#pragma unroll 1
    for (int kt = 0; kt < nkt; ++kt) {
      const int cur = kt & 1;
      if (kt + 1 < nkt) {
        const size_t kbase = (size_t)(kt + 1) * 8192, vbase = (size_t)(kt + 1) * 64;
#pragma unroll
        for (int i = 0; i < 4; ++i) {
          gload_lds16(kb + kbase + koff[i], (char*)&lK[cur ^ 1][0] + (wid * 4 + i) * 1024);
          gload_lds16(vb + vbase + voff[i], (char*)&lV[cur ^ 1][0] + (wid * 4 + i) * 1024);
        }
        asm volatile("s_waitcnt vmcnt(8)" ::: "memory");  // current tile landed, next in flight
      } else {
        asm volatile("s_waitcnt vmcnt(0)" ::: "memory");
      }
      block_barrier();

      // S = Q @ K^T (q pre-scaled)
      f32x4 S[4];
#pragma unroll
      for (int nf = 0; nf < 4; ++nf) S[nf] = zero;
#pragma unroll
      for (int kk = 0; kk < 4; ++kk) {
        short8 kf[4];
#pragma unroll
        for (int nf = 0; nf < 4; ++nf)
          kf[nf] = *(const short8*)&lK[cur][(nf * 16 + r) * 128 + ((kk * 4 + kq) ^ r7) * 8];
#pragma unroll
        for (int nf = 0; nf < 4; ++nf)
          S[nf] = __builtin_amdgcn_mfma_f32_16x16x32_bf16(qa[kk], kf[nf], S[nf], 0, 0, 0);
      }

      // P = exp2(S) un-normalized (0 where masked)
      const bool diag = (kt == nkt - 1);
#pragma unroll
      for (int nf = 0; nf < 4; ++nf)
#pragma unroll
        for (int i = 0; i < 4; ++i) {
          float pv = exp2f(S[nf][i]);
          if (diag) {
            int kg = kt * 64 + nf * 16 + r;
            int qg = q0 + wrow + kq * 4 + i;
            pv = (kg > qg) ? 0.f : pv;
          }
          lp[i] += pv;
          int row = wrow + kq * 4 + i;
          int cl = (nf * 2 + (r >> 3)) ^ ((kq * 4 + i) & 7);
          lP[row * 64 + cl * 8 + r7] = (short)f2bf(pv);
        }

      // O += P @ V^T (P rows wave-private; V read-only under barriers)
#pragma unroll
      for (int kk = 0; kk < 2; ++kk) {
        short8 pa = *(const short8*)&lP[(wrow + r) * 64 + ((kk * 4 + kq) ^ r7) * 8];
#pragma unroll
        for (int nf = 0; nf < 8; ++nf) {
          short8 vf = *(const short8*)&lV[cur][(nf * 16 + r) * 64 + ((kk * 4 + kq) ^ r7) * 8];
          O[nf] = __builtin_amdgcn_mfma_f32_16x16x32_bf16(pa, vf, O[nf], 0, 0, 0);
        }
      }
      asm volatile("s_waitcnt lgkmcnt(0)" ::: "memory");
      block_barrier();  // all reads done before next stage overwrites
    }

    // finalize: one deferred row-sum reduce, then O/l
    float inv[4];
#pragma unroll
    for (int i = 0; i < 4; ++i) {
      float v = lp[i];
      v += __shfl_xor(v, 1);
      v += __shfl_xor(v, 2);
      v += __shfl_xor(v, 4);
      v += __shfl_xor(v, 8);
      inv[i] = 1.f / v;
    }
#pragma unroll
    for (int nf = 0; nf < 8; ++nf)
#pragma unroll
      for (int i = 0; i < 4; ++i) {
        int qg = q0 + wrow + kq * 4 + i;
        out[(size_t)(b * 2048 + qg) * 2048 + h * 128 + nf * 16 + r] = f2bf(O[nf][i] * inv[i]);
      }
  }
}

extern "C" void kernel_launch(void* const* d_in, const int* in_sizes, int n_in,
                              void* d_out, int out_size, void* d_ws, size_t ws_size,
                              hipStream_t stream) {
  const float* x      = (const float*)d_in[0];
  const float* W_attn = (const float*)d_in[1];
  const float* b_attn = (const float*)d_in[2];
  const float* W_proj = (const float*)d_in[3];
  const float* b_proj = (const float*)d_in[4];
  float* y = (float*)d_out;

  // workspace carve-up (bf16 buffers), total 160 MB
  u16* xb     = (u16*)d_ws;                      // [4096][2048]   MB  0-16
  u16* wqkvT  = xb     + (size_t)4096 * 2048;    // [6144][2048]   MB 16-40
  u16* wprojT = wqkvT  + (size_t)6144 * 2048;    // [2048][2048]   MB 40-48
  u16* qkv    = wprojT + (size_t)2048 * 2048;    // (free region)  MB 48-96
  u16* qh     = qkv    + (size_t)4096 * 6144;    // [32][2048][128] 96-112
  u16* kh     = qh     + (size_t)4096 * 2048;    //               112-128
  u16* vt     = kh     + (size_t)4096 * 2048;    // [32][128][2048] 128-144
  u16* attout = vt     + (size_t)4096 * 2048;    // [4096][2048]  144-160
  if (ws_size < (size_t)83886080 * 2) return;    // need 160 MB

  // proj split-K fp32 partials (64 MB) alias the free region
  float* pproj = (float*)qkv;

  k_conv<<<8192, 256, 0, stream>>>(x, xb, 2097152);
  k_tconv<<<dim3(192, 64), dim3(32, 8), 0, stream>>>(W_attn, wqkvT, 2048, 6144);
  k_tconv<<<dim3(64, 64), dim3(32, 8), 0, stream>>>(W_proj, wprojT, 2048, 2048);
  k_gemmqkv<<<dim3(16, 24), 512, 0, stream>>>(xb, wqkvT, b_attn, qh, kh, vt);
  k_attn<<<dim3(16, 16, 2), 256, 0, stream>>>(qh, kh, vt, attout);
  k_gemm3<false, true><<<dim3(16, 8, 2), 512, 0, stream>>>(attout, wprojT, b_proj, pproj, 4096, 2048, 2048, 16);
  k_fadd<<<2048, 256, 0, stream>>>(pproj, b_proj, y, 2097152);
}

// Round 12
// 297.122 us; speedup vs baseline: 1.2490x; 1.0763x over previous
//
#include <hip/hip_runtime.h>
#include <stdint.h>

typedef unsigned short u16;
typedef __attribute__((ext_vector_type(8))) short short8;
typedef __attribute__((ext_vector_type(4))) float f32x4;
typedef __attribute__((ext_vector_type(4))) unsigned short u16x4;

#define DEV __device__ __forceinline__

DEV u16 f2bf(float f) {
  union { float f; unsigned u; } v; v.f = f;
  unsigned r = v.u + 0x7fffu + ((v.u >> 16) & 1u);
  return (u16)(r >> 16);
}
DEV float bf2f(u16 b) {
  union { unsigned u; float f; } v; v.u = ((unsigned)b) << 16;
  return v.f;
}
DEV void gload_lds16(const void* g, void* l) {
  __builtin_amdgcn_global_load_lds((const __attribute__((address_space(1))) void*)g,
                                   (__attribute__((address_space(3))) void*)l,
                                   16, 0, 0);
}
// raw barrier: no compiler-inserted vmcnt(0) drain (unlike __syncthreads)
DEV void block_barrier() {
  asm volatile("" ::: "memory");
  __builtin_amdgcn_s_barrier();
  asm volatile("" ::: "memory");
}

// ---------------- elementwise f32 -> bf16 (vectorized) ----------------
__global__ void k_conv(const float* __restrict__ in, u16* __restrict__ out, int n4) {
  int i = blockIdx.x * blockDim.x + threadIdx.x;
  if (i >= n4) return;
  const f32x4 v = *(const f32x4*)(in + (size_t)i * 4);
  u16x4 o;
  o[0] = f2bf(v[0]); o[1] = f2bf(v[1]); o[2] = f2bf(v[2]); o[3] = f2bf(v[3]);
  *(u16x4*)(out + (size_t)i * 4) = o;
}

// ---------------- transpose + convert: in f32 [R][C] -> out bf16 [C][R] ----------------
__global__ void k_tconv(const float* __restrict__ in, u16* __restrict__ out, int R, int C) {
  __shared__ float tile[32][33];
  int c0 = blockIdx.x * 32, r0 = blockIdx.y * 32;
  int tx = threadIdx.x, ty = threadIdx.y;
#pragma unroll
  for (int j = 0; j < 32; j += 8)
    tile[ty + j][tx] = in[(size_t)(r0 + ty + j) * C + (c0 + tx)];
  __syncthreads();
#pragma unroll
  for (int j = 0; j < 32; j += 8)
    out[(size_t)(c0 + ty + j) * R + (r0 + tx)] = f2bf(tile[tx][ty + j]);
}

// ---------------- RoPE cos/sin table: [t=2048][dd=64] f32, cos then sin ------
__global__ void k_rtab(float* __restrict__ ct, float* __restrict__ st) {
  int id = blockIdx.x * 256 + threadIdx.x;   // 131072 entries
  int t = id >> 6, dd = id & 63;
  float inv = exp2f((float)dd * -0.20762050593045077f);  // 10000^(-dd/64)
  float s, c;
  sincosf((float)t * inv, &s, &c);
  ct[id] = c; st[id] = s;
}

// ======== QKV GEMM with fused RoPE/head-split/V-transpose epilogue v3 ========
// Main loop: 256x256, even 4-phase, counted vmcnt, T2 swizzle (= k_gemm3).
// Epilogue: stage 256x256 bf16 tile in the GEMM's 128 KB LDS, bank-swizzled;
// q/k rows get RoPE via the precomputed f32 cos/sin TABLE (replaces 128
// sincosf/thread -- round-11 VALU hotspot); q pre-scaled by 1/sqrt(128)*log2e.
// v columns -> vt with 512 B contiguous t-runs.
__global__ __launch_bounds__(512, 2) void k_gemmqkv(const u16* __restrict__ A,
                                                    const u16* __restrict__ Bt,
                                                    const float* __restrict__ bias,
                                                    u16* __restrict__ qh,
                                                    u16* __restrict__ kh,
                                                    u16* __restrict__ vt,
                                                    const float* __restrict__ rtab) {
  const int Kld = 2048, nt = 32;
  __shared__ __align__(16) short smem[4][256 * 64];  // [0..1]=lA dbuf, [2..3]=lB dbuf
  const int tid = threadIdx.x;
  const int wid = tid >> 6, lane = tid & 63;
  const int gx = gridDim.x;
  const int nwg = gx * gridDim.y;
  const int orig = blockIdx.y * gx + blockIdx.x;
  const int lg = (orig & 7) * (nwg >> 3) + (orig >> 3);
  const int bm = (lg % gx) * 256, bn = (lg / gx) * 256;
  const int wr = wid >> 2, wc = wid & 3;            // 2M x 4N wave grid
  const int r = lane & 15, kq = lane >> 4, r7 = lane & 7;

  int aoff[4], boff[4], lbase[4];
#pragma unroll
  for (int j = 0; j < 4; ++j) {
    int c = j * 512 + wid * 64 + lane;
    int row = c >> 3, ch = c & 7;
    aoff[j] = (bm + row) * Kld + (ch ^ (row & 7)) * 8;
    boff[j] = (bn + row) * Kld + (ch ^ (row & 7)) * 8;
    lbase[j] = (j * 512 + wid * 64) * 16;           // wave-uniform LDS byte base
  }

#define STG_A(k0, buf, j) gload_lds16(A + aoff[j] + (k0), (char*)&smem[(buf)][0] + lbase[j])
#define STG_B(k0, buf, j) gload_lds16(Bt + boff[j] + (k0), (char*)&smem[2 + (buf)][0] + lbase[j])
#define RD_A(AF, MH, KK)                                                        \
  _Pragma("unroll")                                                             \
  for (int m2 = 0; m2 < 4; ++m2)                                                \
    AF[m2] = *(const short8*)&As[(wr * 128 + (MH) * 64 + m2 * 16 + r) * 64      \
                                 + (((KK) * 4 + kq) ^ r7) * 8];
#define RD_B(KK)                                                                \
  _Pragma("unroll")                                                             \
  for (int nf = 0; nf < 4; ++nf)                                                \
    bfr[KK][nf] = *(const short8*)&Bs[(wc * 64 + nf * 16 + r) * 64              \
                                      + (((KK) * 4 + kq) ^ r7) * 8];
#define PH_MFMA(AF, MH, KK)                                                     \
  __builtin_amdgcn_s_setprio(1);                                                \
  _Pragma("unroll")                                                             \
  for (int m2 = 0; m2 < 4; ++m2)                                                \
    _Pragma("unroll")                                                           \
    for (int nf = 0; nf < 4; ++nf)                                              \
      acc[(MH) * 4 + m2][nf] = __builtin_amdgcn_mfma_f32_16x16x32_bf16(         \
          AF[m2], bfr[KK][nf], acc[(MH) * 4 + m2][nf], 0, 0, 0);                \
  __builtin_amdgcn_s_setprio(0);

  f32x4 acc[8][4];
  const f32x4 zero = {0.f, 0.f, 0.f, 0.f};
#pragma unroll
  for (int i = 0; i < 8; ++i)
#pragma unroll
    for (int j = 0; j < 4; ++j) acc[i][j] = zero;

#pragma unroll
  for (int j = 0; j < 4; ++j) STG_A(0, 0, j);
#pragma unroll
  for (int j = 0; j < 4; ++j) STG_B(0, 0, j);
#pragma unroll
  for (int j = 0; j < 4; ++j) STG_B(64, 1, j);
  asm volatile("s_waitcnt vmcnt(4)" ::: "memory");
  block_barrier();

#pragma unroll 1
  for (int t = 0; t < nt; ++t) {
    const int cur = t & 1, nxt = cur ^ 1;
    const short* As = &smem[cur][0];
    const short* Bs = &smem[2 + cur][0];
    const int kA = (t + 1) * 64, kB = (t + 2) * 64;
    const bool sA = (t + 1 < nt), sB = (t + 2 < nt);
    short8 bfr[2][4];
    short8 af[4];

    RD_B(0)
    RD_A(af, 0, 0)
    if (sA) { STG_A(kA, nxt, 0); STG_A(kA, nxt, 1); }
    block_barrier();
    PH_MFMA(af, 0, 0)
    block_barrier();

    RD_B(1)
    RD_A(af, 0, 1)
    if (sA) { STG_A(kA, nxt, 2); STG_A(kA, nxt, 3); }
    block_barrier();
    PH_MFMA(af, 0, 1)
    block_barrier();

    RD_A(af, 1, 0)
    if (sB) { STG_B(kB, cur, 0); STG_B(kB, cur, 1); }
    block_barrier();
    PH_MFMA(af, 1, 0)
    block_barrier();

    RD_A(af, 1, 1)
    if (sB) { STG_B(kB, cur, 2); STG_B(kB, cur, 3); }
    block_barrier();
    PH_MFMA(af, 1, 1)
    if (t + 1 < nt) {
      if (sB) asm volatile("s_waitcnt vmcnt(4)" ::: "memory");
      else    asm volatile("s_waitcnt vmcnt(0)" ::: "memory");
    }
    block_barrier();
  }
#undef STG_A
#undef STG_B
#undef RD_A
#undef RD_B
#undef PH_MFMA

  // -------- fused epilogue (LDS-staged, coalesced writes) --------
  const int by = lg / gx;            // 0..23
  const int part = by >> 3;          // 0=q, 1=k, 2=v
  const int b_ = bm >> 11;           // batch
  const int tb = bm & 2047;          // t base (block never crosses batch)
  const int hbase = (bn & 2047) >> 7;
  u16* ob = (u16*)&smem[0][0];       // 128 KB staging [256 ml][256 cl]

  // write phase: biased values -> ob (swizzled)
#pragma unroll
  for (int nf = 0; nf < 4; ++nf) {
    int nl = wc * 64 + nf * 16 + r;
    float bv = bias[bn + nl];
#pragma unroll
    for (int mf = 0; mf < 8; ++mf) {
      int mlb = wr * 128 + mf * 16 + kq * 4;
#pragma unroll
      for (int i = 0; i < 4; ++i) {
        int ml = mlb + i;
        int cl = (part == 2)
          ? (nl ^ (((ml >> 2) & 3) << 4) ^ (((ml >> 4) & 7) << 1))
          : (nl ^ (((ml >> 2) & 3) << 4));
        ob[ml * 256 + cl] = f2bf(acc[mf][nf][i] + bv);
      }
    }
  }
  block_barrier();

  if (part == 2) {
    // V: wave reads column dl = iter*8+wid; stores 512 B t-runs into vt
#pragma unroll 1
    for (int iter = 0; iter < 32; ++iter) {
      int dl = iter * 8 + wid;
      int hh = hbase + (dl >> 7), d = dl & 127;
      int tl4 = lane * 4;
      int cl = dl ^ ((lane & 3) << 4) ^ (((lane >> 2) & 7) << 1);
      u16x4 o;
#pragma unroll
      for (int j = 0; j < 4; ++j) o[j] = ob[(tl4 + j) * 256 + cl];
      *(u16x4*)(vt + ((size_t)(b_ * 16 + hh) * 128 + d) * 2048 + tb + tl4) = o;
    }
  } else {
    // q/k: wave reads row tl = iter*8+wid; RoPE pair (d, d^64) same row.
    // Trig from the f32 table (two dwordx4 loads / iter, L2-resident);
    // q additionally pre-scaled by 1/sqrt(128)*log2(e) for attn's exp2.
    u16* dst = part ? kh : qh;
    const float qscale = part ? 1.0f : 0.12751744766834352f;
    const int nl2 = lane * 4;
    const int hh = hbase + (nl2 >> 7);
    const int d0 = nl2 & 127;
    const int hi = (nl2 >> 6) & 1;
    const int dd4 = nl2 & 63;
    const float* ct = rtab;
    const float* st = rtab + 131072;
#pragma unroll 2
    for (int iter = 0; iter < 32; ++iter) {
      int tl = iter * 8 + wid;
      int tg = tb + tl;
      f32x4 c4 = *(const f32x4*)(ct + tg * 64 + dd4);
      f32x4 s4 = *(const f32x4*)(st + tg * 64 + dd4);
      int xr = ((tl >> 2) & 3) << 4;
      int base = tl * 256 + (nl2 ^ xr);
      int pbase = tl * 256 + ((nl2 ^ 64) ^ xr);
      u16x4 o;
#pragma unroll
      for (int j = 0; j < 4; ++j) {
        float vo = bf2f(ob[base + j]);
        float vp = bf2f(ob[pbase + j]);
        float vr = hi ? (vo * c4[j] + vp * s4[j]) : (vo * c4[j] - vp * s4[j]);
        o[j] = f2bf(vr * qscale);
      }
      *(u16x4*)(dst + ((size_t)(b_ * 16 + hh) * 2048 + tg) * 128 + d0) = o;
    }
  }
}

// ---------------- GEMM TN v4 (proj split-K): 256x256, even 4-phase ----------
template <bool OUT_BF16, bool SPLITK>
__global__ __launch_bounds__(512, 2) void k_gemm3(const u16* __restrict__ A,
                                                  const u16* __restrict__ Bt,
                                                  const float* __restrict__ bias,
                                                  void* __restrict__ Cv,
                                                  int M, int N, int Kld, int nkt) {
  __shared__ __align__(16) short lA[2][256 * 64];   // 2 x 32 KB
  __shared__ __align__(16) short lB[2][256 * 64];   // 2 x 32 KB
  const int tid = threadIdx.x;
  const int wid = tid >> 6, lane = tid & 63;
  const int gx = gridDim.x;
  const int nwg = gx * gridDim.y;
  const int orig = blockIdx.y * gx + blockIdx.x;
  const int lg = (orig & 7) * (nwg >> 3) + (orig >> 3);
  const int bm = (lg % gx) * 256, bn = (lg / gx) * 256;
  const int wr = wid >> 2, wc = wid & 3;            // 2M x 4N wave grid
  const int r = lane & 15, kq = lane >> 4, r7 = lane & 7;
  const int kz = SPLITK ? blockIdx.z * (nkt << 6) : 0;

  int aoff[4], boff[4], lbase[4];
#pragma unroll
  for (int j = 0; j < 4; ++j) {
    int c = j * 512 + wid * 64 + lane;
    int row = c >> 3, ch = c & 7;
    aoff[j] = (bm + row) * Kld + kz + (ch ^ (row & 7)) * 8;
    boff[j] = (bn + row) * Kld + kz + (ch ^ (row & 7)) * 8;
    lbase[j] = (j * 512 + wid * 64) * 16;           // wave-uniform LDS byte base
  }

#define STG_A(k0, buf, j) gload_lds16(A + aoff[j] + (k0), (char*)&lA[(buf)][0] + lbase[j])
#define STG_B(k0, buf, j) gload_lds16(Bt + boff[j] + (k0), (char*)&lB[(buf)][0] + lbase[j])
#define RD_A(AF, MH, KK)                                                        \
  _Pragma("unroll")                                                             \
  for (int m2 = 0; m2 < 4; ++m2)                                                \
    AF[m2] = *(const short8*)&As[(wr * 128 + (MH) * 64 + m2 * 16 + r) * 64      \
                                 + (((KK) * 4 + kq) ^ r7) * 8];
#define RD_B(KK)                                                                \
  _Pragma("unroll")                                                             \
  for (int nf = 0; nf < 4; ++nf)                                                \
    bfr[KK][nf] = *(const short8*)&Bs[(wc * 64 + nf * 16 + r) * 64              \
                                      + (((KK) * 4 + kq) ^ r7) * 8];
#define PH_MFMA(AF, MH, KK)                                                     \
  __builtin_amdgcn_s_setprio(1);                                                \
  _Pragma("unroll")                                                             \
  for (int m2 = 0; m2 < 4; ++m2)                                                \
    _Pragma("unroll")                                                           \
    for (int nf = 0; nf < 4; ++nf)                                              \
      acc[(MH) * 4 + m2][nf] = __builtin_amdgcn_mfma_f32_16x16x32_bf16(         \
          AF[m2], bfr[KK][nf], acc[(MH) * 4 + m2][nf], 0, 0, 0);                \
  __builtin_amdgcn_s_setprio(0);

  f32x4 acc[8][4];
  const f32x4 zero = {0.f, 0.f, 0.f, 0.f};
#pragma unroll
  for (int i = 0; i < 8; ++i)
#pragma unroll
    for (int j = 0; j < 4; ++j) acc[i][j] = zero;

  const int nt = nkt;

#pragma unroll
  for (int j = 0; j < 4; ++j) STG_A(0, 0, j);
#pragma unroll
  for (int j = 0; j < 4; ++j) STG_B(0, 0, j);
  if (nt > 1) {
#pragma unroll
    for (int j = 0; j < 4; ++j) STG_B(64, 1, j);
    asm volatile("s_waitcnt vmcnt(4)" ::: "memory");
  } else {
    asm volatile("s_waitcnt vmcnt(0)" ::: "memory");
  }
  block_barrier();

#pragma unroll 1
  for (int t = 0; t < nt; ++t) {
    const int cur = t & 1, nxt = cur ^ 1;
    const short* As = &lA[cur][0];
    const short* Bs = &lB[cur][0];
    const int kA = (t + 1) * 64, kB = (t + 2) * 64;
    const bool sA = (t + 1 < nt), sB = (t + 2 < nt);
    short8 bfr[2][4];
    short8 af[4];

    RD_B(0)
    RD_A(af, 0, 0)
    if (sA) { STG_A(kA, nxt, 0); STG_A(kA, nxt, 1); }
    block_barrier();
    PH_MFMA(af, 0, 0)
    block_barrier();

    RD_B(1)
    RD_A(af, 0, 1)
    if (sA) { STG_A(kA, nxt, 2); STG_A(kA, nxt, 3); }
    block_barrier();
    PH_MFMA(af, 0, 1)
    block_barrier();

    RD_A(af, 1, 0)
    if (sB) { STG_B(kB, cur, 0); STG_B(kB, cur, 1); }
    block_barrier();
    PH_MFMA(af, 1, 0)
    block_barrier();

    RD_A(af, 1, 1)
    if (sB) { STG_B(kB, cur, 2); STG_B(kB, cur, 3); }
    block_barrier();
    PH_MFMA(af, 1, 1)
    if (t + 1 < nt) {
      if (sB) asm volatile("s_waitcnt vmcnt(4)" ::: "memory");
      else    asm volatile("s_waitcnt vmcnt(0)" ::: "memory");
    }
    block_barrier();
  }
#undef STG_A
#undef STG_B
#undef RD_A
#undef RD_B
#undef PH_MFMA

#pragma unroll
  for (int mf = 0; mf < 8; ++mf)
#pragma unroll
    for (int nf = 0; nf < 4; ++nf) {
      int n = bn + wc * 64 + nf * 16 + r;
      float bv = SPLITK ? 0.f : bias[n];
#pragma unroll
      for (int i = 0; i < 4; ++i) {
        int m = bm + wr * 128 + mf * 16 + kq * 4 + i;
        float val = acc[mf][nf][i] + bv;
        if (SPLITK)
          ((float*)Cv)[(size_t)blockIdx.z * M * N + (size_t)m * N + n] = val;
        else if (OUT_BF16)
          ((u16*)Cv)[(size_t)m * N + n] = f2bf(val);
        else
          ((float*)Cv)[(size_t)m * N + n] = val;
      }
    }
}

// ---------------- split-K reduce: y = p0 + p1 + bias (fp32, N=2048) ----------
__global__ void k_fadd(const float* __restrict__ p, const float* __restrict__ bias,
                       float* __restrict__ y, int n4) {
  const int half4 = 2097152;  // 4096*2048/4
  for (int i = blockIdx.x * blockDim.x + threadIdx.x; i < n4; i += gridDim.x * blockDim.x) {
    f32x4 a = *(const f32x4*)(p + (size_t)i * 4);
    f32x4 b = *(const f32x4*)(p + (size_t)(i + half4) * 4);
    f32x4 bv = *(const f32x4*)(bias + ((i & 511) << 2));
    f32x4 o = a + b + bv;
    *(f32x4*)(y + (size_t)i * 4) = o;
  }
}

// ---------------- causal flash attention v6: QBLK=128, 8-wave blocks ---------
// One K/V staging now feeds 8 waves (was 4): staged volume, gload count and
// barrier count per unit MFMA all halve vs v5. Pairing (J, 15-J) -> every
// block does exactly 34 k-tiles; grid 256 = exactly 1 block/CU. Max-free
// softmax (q pre-scaled, exp2 direct); K+V dbuf gload_lds staging, counted
// vmcnt(4); T2 swizzle. Mask applies to the last TWO tiles (kt >= nkt-2).
__global__ __launch_bounds__(512) void k_attn(const u16* __restrict__ qh,
                                              const u16* __restrict__ kh,
                                              const u16* __restrict__ vt,
                                              u16* __restrict__ out) {
  __shared__ __align__(16) short lK[2][64 * 128];   // 32 KB (swizzled rows of 256 B)
  __shared__ __align__(16) short lV[2][128 * 64];   // 32 KB (swizzled rows of 128 B)
  __shared__ __align__(16) short lP[128 * 64];      // 16 KB (wave-private rows, swizzled)
  const int tid = threadIdx.x, wid = tid >> 6, lane = tid & 63;
  const int p = blockIdx.x, h = blockIdx.y, b = blockIdx.z;
  const size_t bh = (size_t)b * 16 + h;
  const u16* qb = qh + bh * 2048 * 128;
  const u16* kb = kh + bh * 2048 * 128;
  const u16* vb = vt + bh * 128 * 2048;
  const int r = lane & 15, kq = lane >> 4;
  const int r7 = r & 7;
  const int wrow = wid * 16;                        // 0..127

  // staging maps: 512 threads, 2 calls each for K [64][128] and V [128][64]
  int koff[2], voff[2], lbase[2];
#pragma unroll
  for (int i = 0; i < 2; ++i) {
    int c = i * 512 + wid * 64 + lane;
    int krow = c >> 4, kch = c & 15;
    koff[i] = krow * 128 + ((kch ^ (krow & 7)) * 8);
    int vrow = c >> 3, vch = c & 7;
    voff[i] = vrow * 2048 + ((vch ^ (vrow & 7)) * 8);
    lbase[i] = (i * 512 + wid * 64) * 16;           // wave-uniform LDS byte base
  }

#pragma unroll 1
  for (int seg = 0; seg < 2; ++seg) {
    const int J = seg ? 15 - p : p;
    const int q0 = J * 128;
    const int nkt = 2 * J + 2;

    short8 qa[4];
#pragma unroll
    for (int kk = 0; kk < 4; ++kk)
      qa[kk] = *(const short8*)(qb + (size_t)(q0 + wrow + r) * 128 + kk * 32 + kq * 8);

    f32x4 O[8];
    const f32x4 zero = {0.f, 0.f, 0.f, 0.f};
#pragma unroll
    for (int nf = 0; nf < 8; ++nf) O[nf] = zero;
    float lp[4] = {0.f, 0.f, 0.f, 0.f};   // per-lane row-sum partials

    // prologue stage tile 0 -> buf 0 (4 calls: 2 K + 2 V)
#pragma unroll
    for (int i = 0; i < 2; ++i) {
      gload_lds16(kb + koff[i], (char*)&lK[0][0] + lbase[i]);
      gload_lds16(vb + voff[i], (char*)&lV[0][0] + lbase[i]);
    }

#pragma unroll 1
    for (int kt = 0; kt < nkt; ++kt) {
      const int cur = kt & 1;
      if (kt + 1 < nkt) {
        const size_t kbase = (size_t)(kt + 1) * 8192, vbase = (size_t)(kt + 1) * 64;
#pragma unroll
        for (int i = 0; i < 2; ++i) {
          gload_lds16(kb + kbase + koff[i], (char*)&lK[cur ^ 1][0] + lbase[i]);
          gload_lds16(vb + vbase + voff[i], (char*)&lV[cur ^ 1][0] + lbase[i]);
        }
        asm volatile("s_waitcnt vmcnt(4)" ::: "memory");  // tile kt landed; kt+1 in flight
      } else {
        asm volatile("s_waitcnt vmcnt(0)" ::: "memory");
      }
      block_barrier();

      // S = Q @ K^T (q pre-scaled)
      f32x4 S[4];
#pragma unroll
      for (int nf = 0; nf < 4; ++nf) S[nf] = zero;
#pragma unroll
      for (int kk = 0; kk < 4; ++kk) {
        short8 kf[4];
#pragma unroll
        for (int nf = 0; nf < 4; ++nf)
          kf[nf] = *(const short8*)&lK[cur][(nf * 16 + r) * 128 + ((kk * 4 + kq) ^ r7) * 8];
#pragma unroll
        for (int nf = 0; nf < 4; ++nf)
          S[nf] = __builtin_amdgcn_mfma_f32_16x16x32_bf16(qa[kk], kf[nf], S[nf], 0, 0, 0);
      }

      // P = exp2(S) un-normalized (0 where masked; last two tiles span diag)
      const bool diag = (kt >= nkt - 2);
#pragma unroll
      for (int nf = 0; nf < 4; ++nf)
#pragma unroll
        for (int i = 0; i < 4; ++i) {
          float pv = exp2f(S[nf][i]);
          if (diag) {
            int kg = kt * 64 + nf * 16 + r;
            int qg = q0 + wrow + kq * 4 + i;
            pv = (kg > qg) ? 0.f : pv;
          }
          lp[i] += pv;
          int row = wrow + kq * 4 + i;
          int cl = (nf * 2 + (r >> 3)) ^ ((kq * 4 + i) & 7);
          lP[row * 64 + cl * 8 + r7] = (short)f2bf(pv);
        }

      // O += P @ V^T (P rows wave-private; V read-only under barriers)
#pragma unroll
      for (int kk = 0; kk < 2; ++kk) {
        short8 pa = *(const short8*)&lP[(wrow + r) * 64 + ((kk * 4 + kq) ^ r7) * 8];
#pragma unroll
        for (int nf = 0; nf < 8; ++nf) {
          short8 vf = *(const short8*)&lV[cur][(nf * 16 + r) * 64 + ((kk * 4 + kq) ^ r7) * 8];
          O[nf] = __builtin_amdgcn_mfma_f32_16x16x32_bf16(pa, vf, O[nf], 0, 0, 0);
        }
      }
      asm volatile("s_waitcnt lgkmcnt(0)" ::: "memory");
      block_barrier();  // all reads done before next stage overwrites
    }

    // finalize: one deferred row-sum reduce, then O/l
    float inv[4];
#pragma unroll
    for (int i = 0; i < 4; ++i) {
      float v = lp[i];
      v += __shfl_xor(v, 1);
      v += __shfl_xor(v, 2);
      v += __shfl_xor(v, 4);
      v += __shfl_xor(v, 8);
      inv[i] = 1.f / v;
    }
#pragma unroll
    for (int nf = 0; nf < 8; ++nf)
#pragma unroll
      for (int i = 0; i < 4; ++i) {
        int qg = q0 + wrow + kq * 4 + i;
        out[(size_t)(b * 2048 + qg) * 2048 + h * 128 + nf * 16 + r] = f2bf(O[nf][i] * inv[i]);
      }
  }
}

extern "C" void kernel_launch(void* const* d_in, const int* in_sizes, int n_in,
                              void* d_out, int out_size, void* d_ws, size_t ws_size,
                              hipStream_t stream) {
  const float* x      = (const float*)d_in[0];
  const float* W_attn = (const float*)d_in[1];
  const float* b_attn = (const float*)d_in[2];
  const float* W_proj = (const float*)d_in[3];
  const float* b_proj = (const float*)d_in[4];
  float* y = (float*)d_out;

  // workspace carve-up (bf16 buffers), total 160 MB
  u16* xb     = (u16*)d_ws;                      // [4096][2048]   MB  0-16
  u16* wqkvT  = xb     + (size_t)4096 * 2048;    // [6144][2048]   MB 16-40
  u16* wprojT = wqkvT  + (size_t)6144 * 2048;    // [2048][2048]   MB 40-48
  u16* qkv    = wprojT + (size_t)2048 * 2048;    // (free region)  MB 48-96
  u16* qh     = qkv    + (size_t)4096 * 6144;    // [32][2048][128] 96-112
  u16* kh     = qh     + (size_t)4096 * 2048;    //               112-128
  u16* vt     = kh     + (size_t)4096 * 2048;    // [32][128][2048] 128-144
  u16* attout = vt     + (size_t)4096 * 2048;    // [4096][2048]  144-160
  if (ws_size < (size_t)83886080 * 2) return;    // need 160 MB

  // free-region aliases: RoPE table (1 MB, used only by k_gemmqkv) then
  // proj split-K fp32 partials (64 MB, used after attn)
  float* rtab  = (float*)qkv;
  float* pproj = (float*)qkv;

  k_conv<<<8192, 256, 0, stream>>>(x, xb, 2097152);
  k_tconv<<<dim3(192, 64), dim3(32, 8), 0, stream>>>(W_attn, wqkvT, 2048, 6144);
  k_tconv<<<dim3(64, 64), dim3(32, 8), 0, stream>>>(W_proj, wprojT, 2048, 2048);
  k_rtab<<<512, 256, 0, stream>>>(rtab, rtab + 131072);
  k_gemmqkv<<<dim3(16, 24), 512, 0, stream>>>(xb, wqkvT, b_attn, qh, kh, vt, rtab);
  k_attn<<<dim3(8, 16, 2), 512, 0, stream>>>(qh, kh, vt, attout);
  k_gemm3<false, true><<<dim3(16, 8, 2), 512, 0, stream>>>(attout, wprojT, b_proj, pproj, 4096, 2048, 2048, 16);
  k_fadd<<<2048, 256, 0, stream>>>(pproj, b_proj, y, 2097152);
}